// Round 18
// baseline (6949.888 us; speedup 1.0000x reference)
//
#include <hip/hip_runtime.h>
#include <math.h>

#define NN 2048
constexpr int IMG = NN * NN;

// ---------------------------------------------------------------- helpers

__device__ __forceinline__ float exp32(float x) { return (float)exp((double)x); }

// strict-f32 eigen path, numpy op order, no FMA
struct Eig { float l1, l2; };
__device__ __forceinline__ Eig eig_np(float a, float b, float c) {
    float ht = __fmul_rn(0.5f, __fadd_rn(a, c));
    float hd = __fmul_rn(0.5f, __fsub_rn(a, c));
    float disc = __fsqrt_rn(__fadd_rn(__fmul_rn(hd, hd), __fmul_rn(b, b)));
    float e1 = __fadd_rn(ht, disc);
    float e2 = __fsub_rn(ht, disc);
    bool sw = fabsf(e1) > fabsf(e2);
    Eig r;
    r.l1 = sw ? e2 : e1;     // smaller |.|
    r.l2 = sw ? e1 : e2;     // larger  |.|
    return r;
}

__device__ __forceinline__ float ssq_np(const Eig& e) {
    return __fadd_rn(__fmul_rn(e.l1, e.l1), __fmul_rn(e.l2, e.l2));
}

__device__ __forceinline__ float vessel_np(float a, float b, float c, float gsq) {
    Eig e = eig_np(a, b, c);
    float s2 = ssq_np(e);
    float l2c = fmaxf(e.l2, 1e-10f);
    float rb = __fdiv_rn(__fmul_rn(e.l1, e.l1), __fmul_rn(l2c, l2c));
    float t1 = exp32(__fdiv_rn(-rb, 0.045f));                 // exp(-rb/(2*0.15^2))
    float t2 = __fsub_rn(1.0f, exp32(__fdiv_rn(-s2, gsq)));
    return __fmul_rn(t1, t2);                                 // file order: rb-term * S-term
}

// ---------------------------------------------------------------- init: weights f64-computed, f32-cast (as the file stores them)

__global__ void init_k(float* __restrict__ wk, unsigned* __restrict__ sc) {
    int g = threadIdx.x >> 6;     // 0..5
    int lane = threadIdx.x & 63;
    if (g < 5) {
        int sigma = 10 + 2 * g;
        int r = 4 * sigma;        // int(4.0*sigma + 0.5)
        int K = 2 * r + 1;
        double s2 = (double)sigma * (double)sigma;
        double pv[3], xv[3];
        double psum = 0.0;
#pragma unroll
        for (int it = 0; it < 3; ++it) {
            int j = lane + 64 * it;
            double x = (double)(j - r);
            double p = (j < K) ? exp(-0.5 * x * x / s2) : 0.0;
            pv[it] = p; xv[it] = x;
            psum += p;
        }
        for (int off = 32; off; off >>= 1) psum += __shfl_xor(psum, off);
        float* wsm = wk + g * 320;        // smooth f32
        float* wdr = wsm + 160;           // deriv  f32
#pragma unroll
        for (int it = 0; it < 3; ++it) {
            int j = lane + 64 * it;
            if (j < 160) {
                double p = pv[it] / psum;
                wsm[j] = (float)p;
                wdr[j] = (float)((xv[it] / s2) * p);
            }
        }
    } else if (lane == 0) {
        sc[0] = 0u;             // max s_sq (f32 bits, nonneg -> uint-ordered)
        sc[1] = 0u;             // gamma_sq
        sc[2] = 0x7f800000u;    // min F (+inf)
        sc[3] = 0u;             // max F
    }
}

// ---------------------------------------------------------------- gray (f32, numpy order, no FMA)

__global__ __launch_bounds__(256) void gray_k(const float* __restrict__ img, float* __restrict__ g) {
    int i = blockIdx.x * blockDim.x + threadIdx.x;
    int stride = gridDim.x * blockDim.x;
    for (int k = i; k < IMG; k += stride) {
        float a = img[k], b = img[IMG + k], c = img[2 * IMG + k];
        float t = __fadd_rn(__fadd_rn(__fmul_rn(0.2989f, a), __fmul_rn(0.587f, b)),
                            __fmul_rn(0.114f, c));
        g[k] = -t;   // black_ridges
    }
}

// ---------------------------------------------------------------- conv pass: BLAS sgemv-style row dot (OpenBLAS AVX2 pattern)
// 8 stride-8 accumulator chains over floor(K/8)*8 taps (NO 128-split at any K),
// horizontal combine extract-hi + 2x hadd: ((r0+r4)+(r1+r5)) + ((r2+r6)+(r3+r7)),
// then scalar remainder. Products f32-rounded separately (FMA-vs-not measured
// no-op, r3==r6). f32 store per 1-D pass.

template<int K, bool VERT>
__global__ __launch_bounds__(256) void npconv_k(const float* __restrict__ in,
                                                float* __restrict__ out,
                                                const float* __restrict__ wk) {
    constexpr int R = (K - 1) / 2;
    const int col = blockIdx.x * 256 + threadIdx.x;
    const int row = blockIdx.y;

    auto P = [&](int k) -> float {        // product for tap k, numpy 'symmetric' pad
        int q = (VERT ? row : col) + k - R;
        q = (q < 0) ? (-1 - q) : q;
        q = (q >= NN) ? (2 * NN - 1 - q) : q;
        float x = VERT ? in[q * NN + col] : in[row * NN + q];
        return __fmul_rn(wk[k], x);
    };

    constexpr int NB = (K / 8) * 8;       // 80, 96, 112, 128, 144
    float r0 = 0.f, r1 = 0.f, r2 = 0.f, r3 = 0.f, r4 = 0.f, r5 = 0.f, r6 = 0.f, r7 = 0.f;
    for (int j = 0; j < NB; j += 8) {
        r0 = __fadd_rn(r0, P(j + 0));
        r1 = __fadd_rn(r1, P(j + 1));
        r2 = __fadd_rn(r2, P(j + 2));
        r3 = __fadd_rn(r3, P(j + 3));
        r4 = __fadd_rn(r4, P(j + 4));
        r5 = __fadd_rn(r5, P(j + 5));
        r6 = __fadd_rn(r6, P(j + 6));
        r7 = __fadd_rn(r7, P(j + 7));
    }
    // AVX horizontal: lo128+hi128 -> lanes (l, l+4); hadd; hadd
    float s04 = __fadd_rn(r0, r4);
    float s15 = __fadd_rn(r1, r5);
    float s26 = __fadd_rn(r2, r6);
    float s37 = __fadd_rn(r3, r7);
    float acc = __fadd_rn(__fadd_rn(s04, s15), __fadd_rn(s26, s37));
    for (int j = NB; j < K; ++j) acc = __fadd_rn(acc, P(j));   // remainder (1 tap)

    out[row * NN + col] = acc;
}

// ---------------------------------------------------------------- gamma: max s_sq over first sigma's field (f32, exact file path)

__global__ __launch_bounds__(256) void reduce_ssq_k(const float* __restrict__ hrr,
                                                    const float* __restrict__ hrc,
                                                    const float* __restrict__ hcc,
                                                    unsigned* __restrict__ sc) {
    float m = 0.f;
    int i = blockIdx.x * blockDim.x + threadIdx.x;
    int stride = gridDim.x * blockDim.x;
    for (int k = i; k < IMG; k += stride) {
        Eig e = eig_np(hrr[k], hrc[k], hcc[k]);
        m = fmaxf(m, ssq_np(e));
    }
    for (int off = 32; off; off >>= 1) m = fmaxf(m, __shfl_xor(m, off));
    if ((threadIdx.x & 63) == 0) atomicMax(sc, __float_as_uint(m));
}

__global__ void gamma_k(unsigned* __restrict__ sc) {
    float ms = __uint_as_float(sc[0]);
    float g = __fmul_rn(0.5f, __fsqrt_rn(ms));            // g = 0.5*sqrt(s_sq.max())
    if (g == 0.f) g = 1.f;                                // where(g==0, 1, g)
    ((float*)sc)[1] = __fmul_rn(__fmul_rn(2.0f, g), g);   // 2.0*g*g left-assoc
}

// ---------------------------------------------------------------- vesselness + running max

template<bool FIRST>
__global__ __launch_bounds__(256) void vessel_k(const float* __restrict__ hrr,
                                                const float* __restrict__ hrc,
                                                const float* __restrict__ hcc,
                                                const unsigned* __restrict__ sc,
                                                float* __restrict__ F) {
    const float gsq = __uint_as_float(sc[1]);
    int i = blockIdx.x * blockDim.x + threadIdx.x;
    int stride = gridDim.x * blockDim.x;
    for (int k = i; k < IMG; k += stride) {
        float v = vessel_np(hrr[k], hrc[k], hcc[k], gsq);
        F[k] = FIRST ? v : fmaxf(F[k], v);
    }
}

// ---------------------------------------------------------------- final min/max + normalize (f32, strict)

__global__ __launch_bounds__(256) void minmax_k(const float* __restrict__ F, unsigned* __restrict__ sc) {
    float mn = __uint_as_float(0x7f800000u);
    float mx = 0.f;
    int i = blockIdx.x * blockDim.x + threadIdx.x;
    int stride = gridDim.x * blockDim.x;
    const float4* A = (const float4*)F;
    for (int k = i; k < IMG / 4; k += stride) {
        float4 a = A[k];
        mn = fminf(fminf(mn, fminf(a.x, a.y)), fminf(a.z, a.w));
        mx = fmaxf(fmaxf(mx, fmaxf(a.x, a.y)), fmaxf(a.z, a.w));
    }
    for (int off = 32; off; off >>= 1) {
        mn = fminf(mn, __shfl_xor(mn, off));
        mx = fmaxf(mx, __shfl_xor(mx, off));
    }
    if ((threadIdx.x & 63) == 0) {
        atomicMin(sc + 2, __float_as_uint(mn));
        atomicMax(sc + 3, __float_as_uint(mx));
    }
}

__global__ __launch_bounds__(256) void norm_k(float* __restrict__ F, const unsigned* __restrict__ sc) {
    float mn = __uint_as_float(sc[2]);
    float mx = __uint_as_float(sc[3]);
    float d = __fsub_rn(mx, mn);
    int i = blockIdx.x * blockDim.x + threadIdx.x;
    int stride = gridDim.x * blockDim.x;
    for (int k = i; k < IMG; k += stride) {
        F[k] = __fdiv_rn(__fsub_rn(F[k], mn), d);
    }
}

// ---------------------------------------------------------------- per-sigma driver (exact file pass chain; wks/wkd separate — r7 lesson)

template<int K>
static void run_sigma(const float* G, float* S1, float* S2, float* S3, float* S4,
                      float* F, const float* wks, const float* wkd,
                      unsigned* sc, bool first, hipStream_t stream) {
    dim3 cb(256), cg(NN / 256, NN);
    npconv_k<K, true ><<<cg, cb, 0, stream>>>(G,  S1, wkd);  // Dv(gray)
    npconv_k<K, false><<<cg, cb, 0, stream>>>(S1, S2, wks);  // gr  = Sh(Dv g)
    npconv_k<K, true ><<<cg, cb, 0, stream>>>(G,  S1, wks);  // Sv(gray)
    npconv_k<K, false><<<cg, cb, 0, stream>>>(S1, S3, wkd);  // gc  = Dh(Sv g)
    npconv_k<K, true ><<<cg, cb, 0, stream>>>(S2, S1, wkd);  // Dv(gr)
    npconv_k<K, false><<<cg, cb, 0, stream>>>(S1, S4, wks);  // hrr = Sh(Dv gr)
    npconv_k<K, true ><<<cg, cb, 0, stream>>>(S2, S1, wks);  // Sv(gr)
    npconv_k<K, false><<<cg, cb, 0, stream>>>(S1, S2, wkd);  // hrc = Dh(Sv gr)
    npconv_k<K, true ><<<cg, cb, 0, stream>>>(S3, S1, wks);  // Sv(gc)
    npconv_k<K, false><<<cg, cb, 0, stream>>>(S1, S3, wkd);  // hcc = Dh(Sv gc)
    if (first) {
        reduce_ssq_k<<<1024, 256, 0, stream>>>(S4, S2, S3, sc);
        gamma_k<<<1, 1, 0, stream>>>(sc);
        vessel_k<true ><<<1024, 256, 0, stream>>>(S4, S2, S3, sc, F);
    } else {
        vessel_k<false><<<1024, 256, 0, stream>>>(S4, S2, S3, sc, F);
    }
}

// ---------------------------------------------------------------- entry

extern "C" void kernel_launch(void* const* d_in, const int* in_sizes, int n_in,
                              void* d_out, int out_size, void* d_ws, size_t ws_size,
                              hipStream_t stream) {
    const float* img = (const float*)d_in[0];
    float* F = (float*)d_out;

    size_t need = (size_t)5 * IMG * 4 + 1600 * 4 + 64;
    if (ws_size < need) return;

    float* G  = (float*)d_ws;
    float* S1 = G  + (size_t)IMG;
    float* S2 = S1 + (size_t)IMG;
    float* S3 = S2 + (size_t)IMG;
    float* S4 = S3 + (size_t)IMG;
    float* WK = S4 + (size_t)IMG;
    unsigned* sc = (unsigned*)(WK + 1600);

    init_k<<<dim3(1), dim3(384), 0, stream>>>(WK, sc);
    gray_k<<<dim3(2048), dim3(256), 0, stream>>>(img, G);

    run_sigma<81 >(G, S1, S2, S3, S4, F, WK + 0 * 320, WK + 0 * 320 + 160, sc, true,  stream);
    run_sigma<97 >(G, S1, S2, S3, S4, F, WK + 1 * 320, WK + 1 * 320 + 160, sc, false, stream);
    run_sigma<113>(G, S1, S2, S3, S4, F, WK + 2 * 320, WK + 2 * 320 + 160, sc, false, stream);
    run_sigma<129>(G, S1, S2, S3, S4, F, WK + 3 * 320, WK + 3 * 320 + 160, sc, false, stream);
    run_sigma<145>(G, S1, S2, S3, S4, F, WK + 4 * 320, WK + 4 * 320 + 160, sc, false, stream);

    minmax_k<<<1024, 256, 0, stream>>>(F, sc);
    norm_k<<<2048, 256, 0, stream>>>(F, sc);
}

// Round 19
// 2672.303 us; speedup vs baseline: 2.6007x; 2.6007x over previous
//
#include <hip/hip_runtime.h>
#include <math.h>

#define NN 2048
constexpr int IMG = NN * NN;

// ---------------------------------------------------------------- helpers

__device__ __forceinline__ float exp32(float x) { return (float)exp((double)x); }

// strict-f32 eigen path, numpy op order, no FMA
struct Eig { float l1, l2; };
__device__ __forceinline__ Eig eig_np(float a, float b, float c) {
    float ht = __fmul_rn(0.5f, __fadd_rn(a, c));
    float hd = __fmul_rn(0.5f, __fsub_rn(a, c));
    float disc = __fsqrt_rn(__fadd_rn(__fmul_rn(hd, hd), __fmul_rn(b, b)));
    float e1 = __fadd_rn(ht, disc);
    float e2 = __fsub_rn(ht, disc);
    bool sw = fabsf(e1) > fabsf(e2);
    Eig r;
    r.l1 = sw ? e2 : e1;     // smaller |.|
    r.l2 = sw ? e1 : e2;     // larger  |.|
    return r;
}

__device__ __forceinline__ float ssq_np(const Eig& e) {
    return __fadd_rn(__fmul_rn(e.l1, e.l1), __fmul_rn(e.l2, e.l2));
}

__device__ __forceinline__ float vessel_np(float a, float b, float c, float gsq) {
    Eig e = eig_np(a, b, c);
    float s2 = ssq_np(e);
    float l2c = fmaxf(e.l2, 1e-10f);
    float rb = __fdiv_rn(__fmul_rn(e.l1, e.l1), __fmul_rn(l2c, l2c));
    float t1 = exp32(__fdiv_rn(-rb, 0.045f));                 // exp(-rb/(2*0.15^2))
    float t2 = __fsub_rn(1.0f, exp32(__fdiv_rn(-s2, gsq)));
    return __fmul_rn(t1, t2);                                 // file order: rb-term * S-term
}

// ---------------------------------------------------------------- init: weights f64-computed, f32-cast (as the file stores them)

__global__ void init_k(float* __restrict__ wk, unsigned* __restrict__ sc) {
    int g = threadIdx.x >> 6;     // 0..5
    int lane = threadIdx.x & 63;
    if (g < 5) {
        int sigma = 10 + 2 * g;
        int r = 4 * sigma;        // int(4.0*sigma + 0.5)
        int K = 2 * r + 1;
        double s2 = (double)sigma * (double)sigma;
        double pv[3], xv[3];
        double psum = 0.0;
#pragma unroll
        for (int it = 0; it < 3; ++it) {
            int j = lane + 64 * it;
            double x = (double)(j - r);
            double p = (j < K) ? exp(-0.5 * x * x / s2) : 0.0;
            pv[it] = p; xv[it] = x;
            psum += p;
        }
        for (int off = 32; off; off >>= 1) psum += __shfl_xor(psum, off);
        float* wsm = wk + g * 320;        // smooth f32
        float* wdr = wsm + 160;           // deriv  f32
#pragma unroll
        for (int it = 0; it < 3; ++it) {
            int j = lane + 64 * it;
            if (j < 160) {
                double p = pv[it] / psum;
                wsm[j] = (float)p;
                wdr[j] = (float)((xv[it] / s2) * p);
            }
        }
    } else if (lane == 0) {
        sc[0] = 0u;             // max s_sq (f32 bits, nonneg -> uint-ordered)
        sc[1] = 0u;             // gamma_sq
        sc[2] = 0x7f800000u;    // min F (+inf)
        sc[3] = 0u;             // max F
    }
}

// ---------------------------------------------------------------- gray (f32, numpy order, no FMA)

__global__ __launch_bounds__(256) void gray_k(const float* __restrict__ img, float* __restrict__ g) {
    int i = blockIdx.x * blockDim.x + threadIdx.x;
    int stride = gridDim.x * blockDim.x;
    for (int k = i; k < IMG; k += stride) {
        float a = img[k], b = img[IMG + k], c = img[2 * IMG + k];
        float t = __fadd_rn(__fadd_rn(__fmul_rn(0.2989f, a), __fmul_rn(0.587f, b)),
                            __fmul_rn(0.114f, c));
        g[k] = -t;   // black_ridges
    }
}

// ---------------------------------------------------------------- conv passes: BLAS sgemv tree (r18, bit-exact), restructured for speed
// Per output pixel the FP op sequence is IDENTICAL to r18:
//   8 stride-8 chains over NB=K-1 taps (j ascending, chain j%8, separate mul/add
//   roundings), combine ((r0+r4)+(r1+r5))+((r2+r6)+(r3+r7)), + remainder tap NB.

// Vertical: 4 adjacent cols per thread share one float4 row load; the row
// mirror/address is wave-uniform (scalarized). grid (NN/1024, NN), block 256.
template<int K>
__global__ __launch_bounds__(256) void vpass_k(const float* __restrict__ in,
                                               float* __restrict__ out,
                                               const float* __restrict__ wk) {
    constexpr int R = (K - 1) / 2;
    constexpr int NB = (K / 8) * 8;   // == K-1 (K % 8 == 1)
    const int col4 = (blockIdx.x * 256 + threadIdx.x) * 4;
    const int row = blockIdx.y;

    float r[8][4];
#pragma unroll
    for (int a = 0; a < 8; ++a)
#pragma unroll
        for (int c = 0; c < 4; ++c) r[a][c] = 0.f;

    for (int j0 = 0; j0 < NB; j0 += 8) {
#pragma unroll
        for (int s = 0; s < 8; ++s) {
            int q = row + j0 + s - R;               // uniform per block
            q = (q < 0) ? (-1 - q) : q;             // np.pad 'symmetric'
            q = (q >= NN) ? (2 * NN - 1 - q) : q;
            const float4 v = *(const float4*)(in + (size_t)q * NN + col4);
            const float w = wk[j0 + s];
            r[s][0] = __fadd_rn(r[s][0], __fmul_rn(w, v.x));
            r[s][1] = __fadd_rn(r[s][1], __fmul_rn(w, v.y));
            r[s][2] = __fadd_rn(r[s][2], __fmul_rn(w, v.z));
            r[s][3] = __fadd_rn(r[s][3], __fmul_rn(w, v.w));
        }
    }
    // combine + remainder tap j = NB (row + NB - R == row + R)
    int q = row + NB - R;
    q = (q < 0) ? (-1 - q) : q;
    q = (q >= NN) ? (2 * NN - 1 - q) : q;
    const float4 v = *(const float4*)(in + (size_t)q * NN + col4);
    const float w = wk[NB];
    float4 o4;
    {
        float s04 = __fadd_rn(r[0][0], r[4][0]);
        float s15 = __fadd_rn(r[1][0], r[5][0]);
        float s26 = __fadd_rn(r[2][0], r[6][0]);
        float s37 = __fadd_rn(r[3][0], r[7][0]);
        float acc = __fadd_rn(__fadd_rn(s04, s15), __fadd_rn(s26, s37));
        o4.x = __fadd_rn(acc, __fmul_rn(w, v.x));
    }
    {
        float s04 = __fadd_rn(r[0][1], r[4][1]);
        float s15 = __fadd_rn(r[1][1], r[5][1]);
        float s26 = __fadd_rn(r[2][1], r[6][1]);
        float s37 = __fadd_rn(r[3][1], r[7][1]);
        float acc = __fadd_rn(__fadd_rn(s04, s15), __fadd_rn(s26, s37));
        o4.y = __fadd_rn(acc, __fmul_rn(w, v.y));
    }
    {
        float s04 = __fadd_rn(r[0][2], r[4][2]);
        float s15 = __fadd_rn(r[1][2], r[5][2]);
        float s26 = __fadd_rn(r[2][2], r[6][2]);
        float s37 = __fadd_rn(r[3][2], r[7][2]);
        float acc = __fadd_rn(__fadd_rn(s04, s15), __fadd_rn(s26, s37));
        o4.z = __fadd_rn(acc, __fmul_rn(w, v.z));
    }
    {
        float s04 = __fadd_rn(r[0][3], r[4][3]);
        float s15 = __fadd_rn(r[1][3], r[5][3]);
        float s26 = __fadd_rn(r[2][3], r[6][3]);
        float s37 = __fadd_rn(r[3][3], r[7][3]);
        float acc = __fadd_rn(__fadd_rn(s04, s15), __fadd_rn(s26, s37));
        o4.w = __fadd_rn(acc, __fmul_rn(w, v.w));
    }
    *(float4*)(out + (size_t)row * NN + col4) = o4;
}

// Horizontal: stage mirrored padded row in LDS once; 8 outputs/thread at
// stride 256 (lane-stride-1 LDS reads, conflict-free). grid NN, block 256.
template<int K>
__global__ __launch_bounds__(256) void hpass_k(const float* __restrict__ in,
                                               float* __restrict__ out,
                                               const float* __restrict__ wk) {
    constexpr int R = (K - 1) / 2;
    constexpr int NB = (K / 8) * 8;   // == K-1
    constexpr int FILL = NN + 2 * R;
    __shared__ float lds[FILL];

    const int tid = threadIdx.x;
    const int row = blockIdx.x;
    const float* rin = in + (size_t)row * NN;

    for (int i = tid; i < FILL; i += 256) {
        int p = i - R;
        p = (p < 0) ? (-1 - p) : p;
        p = (p >= NN) ? (2 * NN - 1 - p) : p;
        lds[i] = rin[p];                 // lds[i] == x[mir(i-R)], exact f32 copy
    }
    __syncthreads();

    float r[8][8];                        // [output o][chain]
#pragma unroll
    for (int o = 0; o < 8; ++o)
#pragma unroll
        for (int a = 0; a < 8; ++a) r[o][a] = 0.f;

    for (int j0 = 0; j0 < NB; j0 += 8) {
#pragma unroll
        for (int o = 0; o < 8; ++o) {
            const float* lp = lds + tid + 256 * o + j0;
#pragma unroll
            for (int s = 0; s < 8; ++s)
                r[o][s] = __fadd_rn(r[o][s], __fmul_rn(wk[j0 + s], lp[s]));
        }
    }
    const float w = wk[NB];
#pragma unroll
    for (int o = 0; o < 8; ++o) {
        float s04 = __fadd_rn(r[o][0], r[o][4]);
        float s15 = __fadd_rn(r[o][1], r[o][5]);
        float s26 = __fadd_rn(r[o][2], r[o][6]);
        float s37 = __fadd_rn(r[o][3], r[o][7]);
        float acc = __fadd_rn(__fadd_rn(s04, s15), __fadd_rn(s26, s37));
        acc = __fadd_rn(acc, __fmul_rn(w, lds[tid + 256 * o + NB]));
        out[(size_t)row * NN + tid + 256 * o] = acc;
    }
}

// ---------------------------------------------------------------- gamma: max s_sq over first sigma's field (f32, exact file path)

__global__ __launch_bounds__(256) void reduce_ssq_k(const float* __restrict__ hrr,
                                                    const float* __restrict__ hrc,
                                                    const float* __restrict__ hcc,
                                                    unsigned* __restrict__ sc) {
    float m = 0.f;
    int i = blockIdx.x * blockDim.x + threadIdx.x;
    int stride = gridDim.x * blockDim.x;
    for (int k = i; k < IMG; k += stride) {
        Eig e = eig_np(hrr[k], hrc[k], hcc[k]);
        m = fmaxf(m, ssq_np(e));
    }
    for (int off = 32; off; off >>= 1) m = fmaxf(m, __shfl_xor(m, off));
    if ((threadIdx.x & 63) == 0) atomicMax(sc, __float_as_uint(m));
}

__global__ void gamma_k(unsigned* __restrict__ sc) {
    float ms = __uint_as_float(sc[0]);
    float g = __fmul_rn(0.5f, __fsqrt_rn(ms));            // g = 0.5*sqrt(s_sq.max())
    if (g == 0.f) g = 1.f;                                // where(g==0, 1, g)
    ((float*)sc)[1] = __fmul_rn(__fmul_rn(2.0f, g), g);   // 2.0*g*g left-assoc
}

// ---------------------------------------------------------------- vesselness + running max

template<bool FIRST>
__global__ __launch_bounds__(256) void vessel_k(const float* __restrict__ hrr,
                                                const float* __restrict__ hrc,
                                                const float* __restrict__ hcc,
                                                const unsigned* __restrict__ sc,
                                                float* __restrict__ F) {
    const float gsq = __uint_as_float(sc[1]);
    int i = blockIdx.x * blockDim.x + threadIdx.x;
    int stride = gridDim.x * blockDim.x;
    for (int k = i; k < IMG; k += stride) {
        float v = vessel_np(hrr[k], hrc[k], hcc[k], gsq);
        F[k] = FIRST ? v : fmaxf(F[k], v);
    }
}

// ---------------------------------------------------------------- final min/max + normalize (f32, strict)

__global__ __launch_bounds__(256) void minmax_k(const float* __restrict__ F, unsigned* __restrict__ sc) {
    float mn = __uint_as_float(0x7f800000u);
    float mx = 0.f;
    int i = blockIdx.x * blockDim.x + threadIdx.x;
    int stride = gridDim.x * blockDim.x;
    const float4* A = (const float4*)F;
    for (int k = i; k < IMG / 4; k += stride) {
        float4 a = A[k];
        mn = fminf(fminf(mn, fminf(a.x, a.y)), fminf(a.z, a.w));
        mx = fmaxf(fmaxf(mx, fmaxf(a.x, a.y)), fmaxf(a.z, a.w));
    }
    for (int off = 32; off; off >>= 1) {
        mn = fminf(mn, __shfl_xor(mn, off));
        mx = fmaxf(mx, __shfl_xor(mx, off));
    }
    if ((threadIdx.x & 63) == 0) {
        atomicMin(sc + 2, __float_as_uint(mn));
        atomicMax(sc + 3, __float_as_uint(mx));
    }
}

__global__ __launch_bounds__(256) void norm_k(float* __restrict__ F, const unsigned* __restrict__ sc) {
    float mn = __uint_as_float(sc[2]);
    float mx = __uint_as_float(sc[3]);
    float d = __fsub_rn(mx, mn);
    int i = blockIdx.x * blockDim.x + threadIdx.x;
    int stride = gridDim.x * blockDim.x;
    for (int k = i; k < IMG; k += stride) {
        F[k] = __fdiv_rn(__fsub_rn(F[k], mn), d);
    }
}

// ---------------------------------------------------------------- per-sigma driver (exact file pass chain; wks/wkd separate — r7 lesson)

template<int K>
static void run_sigma(const float* G, float* S1, float* S2, float* S3, float* S4,
                      float* F, const float* wks, const float* wkd,
                      unsigned* sc, bool first, hipStream_t stream) {
    dim3 vb(256), vg(NN / 1024, NN);
    dim3 hb(256), hg(NN);
    vpass_k<K><<<vg, vb, 0, stream>>>(G,  S1, wkd);  // Dv(gray)
    hpass_k<K><<<hg, hb, 0, stream>>>(S1, S2, wks);  // gr  = Sh(Dv g)
    vpass_k<K><<<vg, vb, 0, stream>>>(G,  S1, wks);  // Sv(gray)
    hpass_k<K><<<hg, hb, 0, stream>>>(S1, S3, wkd);  // gc  = Dh(Sv g)
    vpass_k<K><<<vg, vb, 0, stream>>>(S2, S1, wkd);  // Dv(gr)
    hpass_k<K><<<hg, hb, 0, stream>>>(S1, S4, wks);  // hrr = Sh(Dv gr)
    vpass_k<K><<<vg, vb, 0, stream>>>(S2, S1, wks);  // Sv(gr)
    hpass_k<K><<<hg, hb, 0, stream>>>(S1, S2, wkd);  // hrc = Dh(Sv gr)
    vpass_k<K><<<vg, vb, 0, stream>>>(S3, S1, wks);  // Sv(gc)
    hpass_k<K><<<hg, hb, 0, stream>>>(S1, S3, wkd);  // hcc = Dh(Sv gc)
    if (first) {
        reduce_ssq_k<<<1024, 256, 0, stream>>>(S4, S2, S3, sc);
        gamma_k<<<1, 1, 0, stream>>>(sc);
        vessel_k<true ><<<1024, 256, 0, stream>>>(S4, S2, S3, sc, F);
    } else {
        vessel_k<false><<<1024, 256, 0, stream>>>(S4, S2, S3, sc, F);
    }
}

// ---------------------------------------------------------------- entry

extern "C" void kernel_launch(void* const* d_in, const int* in_sizes, int n_in,
                              void* d_out, int out_size, void* d_ws, size_t ws_size,
                              hipStream_t stream) {
    const float* img = (const float*)d_in[0];
    float* F = (float*)d_out;

    size_t need = (size_t)5 * IMG * 4 + 1600 * 4 + 64;
    if (ws_size < need) return;

    float* G  = (float*)d_ws;
    float* S1 = G  + (size_t)IMG;
    float* S2 = S1 + (size_t)IMG;
    float* S3 = S2 + (size_t)IMG;
    float* S4 = S3 + (size_t)IMG;
    float* WK = S4 + (size_t)IMG;
    unsigned* sc = (unsigned*)(WK + 1600);

    init_k<<<dim3(1), dim3(384), 0, stream>>>(WK, sc);
    gray_k<<<dim3(2048), dim3(256), 0, stream>>>(img, G);

    run_sigma<81 >(G, S1, S2, S3, S4, F, WK + 0 * 320, WK + 0 * 320 + 160, sc, true,  stream);
    run_sigma<97 >(G, S1, S2, S3, S4, F, WK + 1 * 320, WK + 1 * 320 + 160, sc, false, stream);
    run_sigma<113>(G, S1, S2, S3, S4, F, WK + 2 * 320, WK + 2 * 320 + 160, sc, false, stream);
    run_sigma<129>(G, S1, S2, S3, S4, F, WK + 3 * 320, WK + 3 * 320 + 160, sc, false, stream);
    run_sigma<145>(G, S1, S2, S3, S4, F, WK + 4 * 320, WK + 4 * 320 + 160, sc, false, stream);

    minmax_k<<<1024, 256, 0, stream>>>(F, sc);
    norm_k<<<2048, 256, 0, stream>>>(F, sc);
}